// Round 3
// baseline (267.351 us; speedup 1.0000x reference)
//
#include <hip/hip_runtime.h>
#include <hip/hip_bf16.h>
#include <math.h>

namespace {
constexpr int B_ = 4, N_ = 2048, D_ = 1024, H_ = 16, DH_ = 64;
constexpr int M_ = B_ * N_;   // 8192 rows of x
}

typedef __bf16 bf16x8 __attribute__((ext_vector_type(8)));
typedef __bf16 bf16x4 __attribute__((ext_vector_type(4)));
typedef float  f32x4  __attribute__((ext_vector_type(4)));

__device__ inline void async_copy16(const void* g, void* l) {
    __builtin_amdgcn_global_load_lds(
        (const __attribute__((address_space(1))) unsigned int*)g,
        (__attribute__((address_space(3))) unsigned int*)l, 16, 0, 0);
}

__device__ inline float fast_exp2(float x) {
#if __has_builtin(__builtin_amdgcn_exp2f)
    return __builtin_amdgcn_exp2f(x);
#else
    return exp2f(x);
#endif
}

// XOR swizzle for 128x32 tiles (legacy kernels): 16B chunk column 0..3.
__device__ inline int swz(int row, int c) {
    return c ^ (row & 3) ^ ((row >> 2) & 3);
}

// ---------------------------------------------------------------------------
// cast x (fp32 -> bf16), 8 elements/thread
// ---------------------------------------------------------------------------
__global__ __launch_bounds__(256) void cast_x(
        const float* __restrict__ x, __bf16* __restrict__ xb)
{
    const size_t i = ((size_t)blockIdx.x * 256 + threadIdx.x) * 8;
    const float4 a = *reinterpret_cast<const float4*>(x + i);
    const float4 b = *reinterpret_cast<const float4*>(x + i + 4);
    bf16x8 o;
    o[0] = (__bf16)a.x; o[1] = (__bf16)a.y; o[2] = (__bf16)a.z; o[3] = (__bf16)a.w;
    o[4] = (__bf16)b.x; o[5] = (__bf16)b.y; o[6] = (__bf16)b.z; o[7] = (__bf16)b.w;
    *reinterpret_cast<bf16x8*>(xb + i) = o;
}

// ---------------------------------------------------------------------------
// cast+transpose weights: W[k][n] fp32 -> Wt[n][k] bf16.
// ---------------------------------------------------------------------------
__global__ __launch_bounds__(256) void cast_w(
        const float* __restrict__ Wq, const float* __restrict__ Wk,
        const float* __restrict__ Wv, const float* __restrict__ Wo,
        __bf16* __restrict__ wqkvt, __bf16* __restrict__ wot)
{
    __shared__ float t[64][65];
    const int z = blockIdx.z;
    const float* W = (z == 0) ? Wq : (z == 1) ? Wk : (z == 2) ? Wv : Wo;
    __bf16* dst = (z < 3) ? (wqkvt + (size_t)z * D_ * D_) : wot;
    const int k0 = blockIdx.x * 64, n0 = blockIdx.y * 64;
    const int tid = threadIdx.x;
    #pragma unroll
    for (int p = 0; p < 16; ++p) {
        const int idx = p * 256 + tid;
        const int r = idx >> 6, c = idx & 63;
        t[r][c] = W[(size_t)(k0 + r) * D_ + n0 + c];
    }
    __syncthreads();
    #pragma unroll
    for (int p = 0; p < 16; ++p) {
        const int idx = p * 256 + tid;
        const int r = idx >> 6, c = idx & 63;
        dst[(size_t)(n0 + r) * D_ + k0 + c] = (__bf16)t[c][r];
    }
}

// ---------------------------------------------------------------------------
// qkv GEMM v2: 256x256 tile, BK=64, 8 waves (512 thr), double-buffered LDS
// (128 KB), 4 phases/K-tile (one C-quadrant each: 12 ds_read_b128 + 16 MFMA +
// raw s_barrier), depth-2 prefetch with counted s_waitcnt vmcnt(8) (never 0
// in steady state). LDS swizzle: 16B chunk c stored at c^(row&7) — every
// 8-lane b128 group covers all 8 bank quads (conflict-free); applied via
// pre-swizzled GLOBAL source + linear global_load_lds dest (rule 21).
// Q epilogue folds 1/sqrt(DH)*log2(e).
// ---------------------------------------------------------------------------
__global__ __launch_bounds__(512, 2) void qkv_mfma(
        const __bf16* __restrict__ A, const __bf16* __restrict__ Bt,
        const float* __restrict__ bq, const float* __restrict__ bk,
        const float* __restrict__ bv,
        __bf16* __restrict__ qo, __bf16* __restrict__ ko, __bf16* __restrict__ vo)
{
    __shared__ __align__(16) __bf16 As[2][256 * 64];   // 64 KB
    __shared__ __align__(16) __bf16 Bs[2][256 * 64];   // 64 KB
    const int tid = threadIdx.x;
    const int w = tid >> 6, lane = tid & 63;
    const int l15 = lane & 15, quad = lane >> 4;
    const int wr = w >> 2, wc = w & 3;            // 2x4 wave grid
    const int tm = blockIdx.x * 256;              // M row base
    const int bn = blockIdx.y * 256;              // packed-N row base in Bt

    const __bf16* Ag = A + (size_t)tm * D_;
    const __bf16* Bg = Bt + (size_t)bn * D_;

    f32x4 acc[8][4] = {};

    // stage tile t (K cols t*64..t*64+63) into buf[t&1]; 8 loads/wave.
    auto stage = [&](int t) {
        const int k0 = t * 64;
        __bf16* Ad = As[t & 1];
        __bf16* Bd = Bs[t & 1];
        #pragma unroll
        for (int s = 0; s < 4; ++s) {
            const int idx = s * 512 + tid;
            const int r = idx >> 3, cs = idx & 7;
            const int cl = cs ^ (r & 7);          // pre-swizzled source chunk
            async_copy16(Ag + (size_t)r * D_ + k0 + cl * 8, Ad + idx * 8);
        }
        #pragma unroll
        for (int s = 0; s < 4; ++s) {
            const int idx = s * 512 + tid;
            const int r = idx >> 3, cs = idx & 7;
            const int cl = cs ^ (r & 7);
            async_copy16(Bg + (size_t)r * D_ + k0 + cl * 8, Bd + idx * 8);
        }
    };

    stage(0);
    stage(1);
    asm volatile("s_waitcnt vmcnt(8)" ::: "memory");   // tile 0 landed
    __builtin_amdgcn_s_barrier();
    __builtin_amdgcn_sched_barrier(0);

    for (int t = 0; t < 16; ++t) {
        const __bf16* Ab = As[t & 1];
        const __bf16* Bb = Bs[t & 1];
        #pragma unroll
        for (int q = 0; q < 4; ++q) {
            const int ar0 = wr * 128 + (q >> 1) * 64;   // A rows this phase
            const int bc0 = wc * 64 + (q & 1) * 32;     // B cols this phase
            bf16x8 af[4][2], bf[2][2];
            #pragma unroll
            for (int fr = 0; fr < 4; ++fr) {
                const int row = ar0 + fr * 16 + l15;
                #pragma unroll
                for (int ks = 0; ks < 2; ++ks)
                    af[fr][ks] = *reinterpret_cast<const bf16x8*>(
                        Ab + row * 64 + ((ks * 4 + quad) ^ (row & 7)) * 8);
            }
            #pragma unroll
            for (int nc = 0; nc < 2; ++nc) {
                const int col = bc0 + nc * 16 + l15;
                #pragma unroll
                for (int ks = 0; ks < 2; ++ks)
                    bf[nc][ks] = *reinterpret_cast<const bf16x8*>(
                        Bb + col * 64 + ((ks * 4 + quad) ^ (col & 7)) * 8);
            }
            __builtin_amdgcn_s_setprio(1);
            #pragma unroll
            for (int fr = 0; fr < 4; ++fr)
                #pragma unroll
                for (int nc = 0; nc < 2; ++nc) {
                    f32x4 c = acc[(q >> 1) * 4 + fr][(q & 1) * 2 + nc];
                    c = __builtin_amdgcn_mfma_f32_16x16x32_bf16(af[fr][0], bf[nc][0], c, 0, 0, 0);
                    c = __builtin_amdgcn_mfma_f32_16x16x32_bf16(af[fr][1], bf[nc][1], c, 0, 0, 0);
                    acc[(q >> 1) * 4 + fr][(q & 1) * 2 + nc] = c;
                }
            __builtin_amdgcn_s_setprio(0);
            __builtin_amdgcn_s_barrier();   // q==3: all reads of buf[t&1] done
        }
        if (t < 14) {
            stage(t + 2);                                   // into buf[t&1] (free)
            asm volatile("s_waitcnt vmcnt(8)" ::: "memory"); // tile t+1 landed
        } else if (t == 14) {
            asm volatile("s_waitcnt vmcnt(0)" ::: "memory"); // final drain
        }
        if (t < 15) {
            __builtin_amdgcn_s_barrier();
            __builtin_amdgcn_sched_barrier(0);
        }
    }

    // ---- epilogue ----
    const int z = blockIdx.y >> 2;                 // 0:Q 1:K 2:V
    const float* bias = (z == 0) ? bq : (z == 1) ? bk : bv;
    const int ysec = blockIdx.y & 3;
    const int h = ysec * 4 + wc;                   // head (wave col = one head)
    float bcol[4];
    #pragma unroll
    for (int nc = 0; nc < 4; ++nc) bcol[nc] = bias[h * 64 + nc * 16 + l15];
    const int gr0 = tm + wr * 128;

    if (z < 2) {
        __bf16* dst = (z == 0) ? qo : ko;
        const float sc = (z == 0) ? 0.125f * 1.44269504f : 1.0f;
        #pragma unroll
        for (int mr = 0; mr < 8; ++mr)
            #pragma unroll
            for (int i = 0; i < 4; ++i) {
                const int gr = gr0 + mr * 16 + quad * 4 + i;
                const int b = gr >> 11, tok = gr & (N_ - 1);
                __bf16* row = dst + ((size_t)(b * H_ + h) * N_ + tok) * DH_;
                #pragma unroll
                for (int nc = 0; nc < 4; ++nc)
                    row[nc * 16 + l15] = (__bf16)((acc[mr][nc][i] + bcol[nc]) * sc);
            }
    } else {
        #pragma unroll
        for (int mr = 0; mr < 8; ++mr) {
            const int gr = gr0 + mr * 16 + quad * 4;
            const int b = gr >> 11, tok = gr & (N_ - 1);
            #pragma unroll
            for (int nc = 0; nc < 4; ++nc) {
                const int dh = nc * 16 + l15;
                bf16x4 pv;
                #pragma unroll
                for (int i = 0; i < 4; ++i)
                    pv[i] = (__bf16)(acc[mr][nc][i] + bcol[nc]);
                *reinterpret_cast<bf16x4*>(
                    vo + ((size_t)(b * H_ + h) * DH_ + dh) * N_ + tok) = pv;
            }
        }
    }
}

// ---------------------------------------------------------------------------
// out = ctx(bf16, MxD) @ Wo + bo, fp32 output. (128x128, unchanged)
// ---------------------------------------------------------------------------
__global__ __launch_bounds__(256) void out_mfma(
        const __bf16* __restrict__ A, const __bf16* __restrict__ Bt,
        const float* __restrict__ bias, float* __restrict__ out)
{
    __shared__ __align__(16) __bf16 As[128 * 32];
    __shared__ __align__(16) __bf16 Bs[128 * 32];
    const int tid = threadIdx.x;
    const int w = tid >> 6, lane = tid & 63;
    const int l15 = lane & 15, quad = lane >> 4;
    const int tm = blockIdx.x * 128;
    const int tn = blockIdx.y * 128;

    f32x4 acc[4][4] = {};

    for (int k0 = 0; k0 < D_; k0 += 32) {
        __syncthreads();
        #pragma unroll
        for (int it = 0; it < 2; ++it) {
            const int c = it * 256 + tid;
            const int r = c >> 2, pc = c & 3;
            const int lc = swz(r, pc);
            async_copy16(A + (size_t)(tm + r) * D_ + k0 + lc * 8, As + c * 8);
            async_copy16(Bt + (size_t)(tn + r) * D_ + k0 + lc * 8, Bs + c * 8);
        }
        __syncthreads();

        bf16x8 af[4], bfr[4];
        #pragma unroll
        for (int t = 0; t < 4; ++t) {
            const int row = (w >> 1) * 64 + t * 16 + l15;
            af[t] = *reinterpret_cast<const bf16x8*>(
                As + (row * 4 + swz(row, quad)) * 8);
            const int col = (w & 1) * 64 + t * 16 + l15;
            bfr[t] = *reinterpret_cast<const bf16x8*>(
                Bs + (col * 4 + swz(col, quad)) * 8);
        }
        #pragma unroll
        for (int mt = 0; mt < 4; ++mt)
            #pragma unroll
            for (int nt = 0; nt < 4; ++nt)
                acc[mt][nt] = __builtin_amdgcn_mfma_f32_16x16x32_bf16(
                    af[mt], bfr[nt], acc[mt][nt], 0, 0, 0);
    }

    const int col0 = tn + (w & 1) * 64;
    float bcol[4];
    #pragma unroll
    for (int nt = 0; nt < 4; ++nt) bcol[nt] = bias[col0 + nt * 16 + l15];
    const int gr0 = tm + (w >> 1) * 64;
    #pragma unroll
    for (int mt = 0; mt < 4; ++mt)
        #pragma unroll
        for (int i = 0; i < 4; ++i) {
            const int gr = gr0 + mt * 16 + quad * 4 + i;
            float* row = out + (size_t)gr * D_;
            #pragma unroll
            for (int nt = 0; nt < 4; ++nt)
                row[col0 + nt * 16 + l15] = acc[mt][nt][i] + bcol[nt];
        }
}

// ---------------------------------------------------------------------------
// MFMA flash attention v7 (decorrelated grid + setprio on MFMA clusters).
// ---------------------------------------------------------------------------
__global__ __launch_bounds__(256, 4) void attn(
        const __bf16* __restrict__ Q, const __bf16* __restrict__ K,
        const __bf16* __restrict__ Vt, __bf16* __restrict__ ctx)
{
    const int blk = blockIdx.x;
    const int bh = blk & 63;
    const int qb = ((blk >> 6) + bh) & 15;
    const int tid = threadIdx.x;
    const int w = tid >> 6, lane = tid & 63;
    const int l15 = lane & 15, quad = lane >> 4;
    const int qt0 = qb * 128;

    __shared__ __align__(16) __bf16 Ks[64 * 64];         // [key][d], swizzled
    __shared__ __align__(16) __bf16 Vs[64 * 64];         // [d][key], swizzled
    __shared__ __align__(16) __bf16 Ps[4][2][16 * 72];   // [wave][qc], +8 pad

    bf16x8 bqf[2][2];
    #pragma unroll
    for (int qc = 0; qc < 2; ++qc) {
        const size_t base = ((size_t)bh * N_ + qt0 + w * 32 + qc * 16 + l15) * DH_;
        bqf[qc][0] = *reinterpret_cast<const bf16x8*>(Q + base + quad * 8);
        bqf[qc][1] = *reinterpret_cast<const bf16x8*>(Q + base + 32 + quad * 8);
    }

    f32x4 acc[2][4] = {};
    float l_lane[2] = {0.f, 0.f};

    const __bf16* Kg = K + (size_t)bh * N_ * DH_;
    const __bf16* Vg = Vt + (size_t)bh * DH_ * N_;
    const int nkb = 2 * qb + 2;
    const int sr = lane >> 3;
    const int sc = lane & 7;

    for (int kb = 0; kb < nkb; ++kb) {
        __syncthreads();
        #pragma unroll
        for (int j = 0; j < 2; ++j) {
            const int r = j * 32 + w * 8 + sr;
            const int cl = sc ^ (r & 7);
            async_copy16(Kg + (size_t)(kb * 64 + r) * DH_ + cl * 8,
                         &Ks[(j * 256 + tid) * 8]);
            async_copy16(Vg + (size_t)r * N_ + kb * 64 + cl * 8,
                         &Vs[(j * 256 + tid) * 8]);
        }
        __syncthreads();

        f32x4 st[2][4];
        __builtin_amdgcn_s_setprio(1);
        #pragma unroll
        for (int ct = 0; ct < 4; ++ct) {
            const int row = ct * 16 + l15;
            const bf16x8 ka0 = *reinterpret_cast<const bf16x8*>(
                &Ks[(row * 8 + (quad ^ (row & 7))) * 8]);
            const bf16x8 ka1 = *reinterpret_cast<const bf16x8*>(
                &Ks[(row * 8 + ((quad + 4) ^ (row & 7))) * 8]);
            #pragma unroll
            for (int qc = 0; qc < 2; ++qc) {
                f32x4 t = {};
                t = __builtin_amdgcn_mfma_f32_16x16x32_bf16(ka0, bqf[qc][0], t, 0, 0, 0);
                t = __builtin_amdgcn_mfma_f32_16x16x32_bf16(ka1, bqf[qc][1], t, 0, 0, 0);
                st[qc][ct] = t;
            }
        }
        __builtin_amdgcn_s_setprio(0);
        if (kb >= 2 * qb) {
            #pragma unroll
            for (int qc = 0; qc < 2; ++qc) {
                const int q_glob = qt0 + w * 32 + qc * 16 + l15;
                #pragma unroll
                for (int ct = 0; ct < 4; ++ct)
                    #pragma unroll
                    for (int i = 0; i < 4; ++i) {
                        const int k_glob = kb * 64 + ct * 16 + quad * 4 + i;
                        if (k_glob > q_glob) st[qc][ct][i] = -INFINITY;
                    }
            }
        }

        #pragma unroll
        for (int qc = 0; qc < 2; ++qc) {
            float rs = 0.f;
            #pragma unroll
            for (int ct = 0; ct < 4; ++ct) {
                bf16x4 pk;
                #pragma unroll
                for (int i = 0; i < 4; ++i) {
                    const float p = fast_exp2(st[qc][ct][i]);
                    rs += p;
                    pk[i] = (__bf16)p;
                }
                *reinterpret_cast<bf16x4*>(
                    &Ps[w][qc][l15 * 72 + ct * 16 + quad * 4]) = pk;
            }
            l_lane[qc] += rs;
        }

        bf16x8 pa0[2], pa1[2];
        #pragma unroll
        for (int qc = 0; qc < 2; ++qc) {
            pa0[qc] = *reinterpret_cast<const bf16x8*>(
                &Ps[w][qc][l15 * 72 + quad * 8]);
            pa1[qc] = *reinterpret_cast<const bf16x8*>(
                &Ps[w][qc][l15 * 72 + 32 + quad * 8]);
        }
        __builtin_amdgcn_s_setprio(1);
        #pragma unroll
        for (int ct = 0; ct < 4; ++ct) {
            const int row = ct * 16 + l15;
            const bf16x8 vb0 = *reinterpret_cast<const bf16x8*>(
                &Vs[(row * 8 + (quad ^ (row & 7))) * 8]);
            const bf16x8 vb1 = *reinterpret_cast<const bf16x8*>(
                &Vs[(row * 8 + ((quad + 4) ^ (row & 7))) * 8]);
            #pragma unroll
            for (int qc = 0; qc < 2; ++qc) {
                f32x4 t = acc[qc][ct];
                t = __builtin_amdgcn_mfma_f32_16x16x32_bf16(pa0[qc], vb0, t, 0, 0, 0);
                t = __builtin_amdgcn_mfma_f32_16x16x32_bf16(pa1[qc], vb1, t, 0, 0, 0);
                acc[qc][ct] = t;
            }
        }
        __builtin_amdgcn_s_setprio(0);
    }

    const int b = bh >> 4, h = bh & 15;
    #pragma unroll
    for (int qc = 0; qc < 2; ++qc) {
        float r = l_lane[qc];
        r += __shfl_xor(r, 16);
        r += __shfl_xor(r, 32);
        const float linv = 1.0f / r;
        float lT[4];
        #pragma unroll
        for (int i = 0; i < 4; ++i) lT[i] = __shfl(linv, quad * 4 + i);
        #pragma unroll
        for (int i = 0; i < 4; ++i) {
            const int row = qt0 + w * 32 + qc * 16 + quad * 4 + i;
            __bf16* dst = ctx + ((size_t)b * N_ + row) * D_ + h * DH_;
            #pragma unroll
            for (int ct = 0; ct < 4; ++ct)
                dst[ct * 16 + l15] = (__bf16)(acc[qc][ct][i] * lT[i]);
        }
    }
}

extern "C" void kernel_launch(void* const* d_in, const int* in_sizes, int n_in,
                              void* d_out, int out_size, void* d_ws, size_t ws_size,
                              hipStream_t stream) {
    const float* x  = (const float*)d_in[0];
    const float* Wq = (const float*)d_in[1];
    const float* bq = (const float*)d_in[2];
    const float* Wk = (const float*)d_in[3];
    const float* bk = (const float*)d_in[4];
    const float* Wv = (const float*)d_in[5];
    const float* bv = (const float*)d_in[6];
    const float* Wo = (const float*)d_in[7];
    const float* bo = (const float*)d_in[8];
    float* out = (float*)d_out;

    __bf16* xb    = (__bf16*)d_ws;
    __bf16* wqkvt = xb + (size_t)M_ * D_;
    __bf16* wot   = wqkvt + (size_t)3 * D_ * D_;
    __bf16* q     = wot + (size_t)D_ * D_;
    __bf16* k     = q + (size_t)M_ * D_;
    __bf16* vt    = k + (size_t)M_ * D_;
    __bf16* ctx   = vt + (size_t)M_ * D_;

    cast_x<<<dim3(M_ * D_ / (256 * 8)), 256, 0, stream>>>(x, xb);
    cast_w<<<dim3(16, 16, 4), 256, 0, stream>>>(Wq, Wk, Wv, Wo, wqkvt, wot);
    qkv_mfma<<<dim3(M_ / 256, 3 * D_ / 256), 512, 0, stream>>>(
        xb, wqkvt, bq, bk, bv, q, k, vt);
    attn<<<dim3(1024), 256, 0, stream>>>(q, k, vt, ctx);
    out_mfma<<<dim3(M_ / 128, D_ / 128), 256, 0, stream>>>(ctx, wot, bo, out);
}

// Round 4
// 264.278 us; speedup vs baseline: 1.0116x; 1.0116x over previous
//
#include <hip/hip_runtime.h>
#include <hip/hip_bf16.h>
#include <math.h>

namespace {
constexpr int B_ = 4, N_ = 2048, D_ = 1024, H_ = 16, DH_ = 64;
constexpr int M_ = B_ * N_;   // 8192 rows of x
}

typedef __bf16 bf16x8 __attribute__((ext_vector_type(8)));
typedef __bf16 bf16x4 __attribute__((ext_vector_type(4)));
typedef float  f32x4  __attribute__((ext_vector_type(4)));

__device__ inline void async_copy16(const void* g, void* l) {
    __builtin_amdgcn_global_load_lds(
        (const __attribute__((address_space(1))) unsigned int*)g,
        (__attribute__((address_space(3))) unsigned int*)l, 16, 0, 0);
}

__device__ inline float fast_exp2(float x) {
#if __has_builtin(__builtin_amdgcn_exp2f)
    return __builtin_amdgcn_exp2f(x);
#else
    return exp2f(x);
#endif
}

// XOR swizzle for 128x32 tiles (legacy kernels): 16B chunk column 0..3.
__device__ inline int swz(int row, int c) {
    return c ^ (row & 3) ^ ((row >> 2) & 3);
}

// ---------------------------------------------------------------------------
// cast x (fp32 -> bf16), 8 elements/thread
// ---------------------------------------------------------------------------
__global__ __launch_bounds__(256) void cast_x(
        const float* __restrict__ x, __bf16* __restrict__ xb)
{
    const size_t i = ((size_t)blockIdx.x * 256 + threadIdx.x) * 8;
    const float4 a = *reinterpret_cast<const float4*>(x + i);
    const float4 b = *reinterpret_cast<const float4*>(x + i + 4);
    bf16x8 o;
    o[0] = (__bf16)a.x; o[1] = (__bf16)a.y; o[2] = (__bf16)a.z; o[3] = (__bf16)a.w;
    o[4] = (__bf16)b.x; o[5] = (__bf16)b.y; o[6] = (__bf16)b.z; o[7] = (__bf16)b.w;
    *reinterpret_cast<bf16x8*>(xb + i) = o;
}

// ---------------------------------------------------------------------------
// cast+transpose weights: W[k][n] fp32 -> Wt[n][k] bf16.
// ---------------------------------------------------------------------------
__global__ __launch_bounds__(256) void cast_w(
        const float* __restrict__ Wq, const float* __restrict__ Wk,
        const float* __restrict__ Wv, const float* __restrict__ Wo,
        __bf16* __restrict__ wqkvt, __bf16* __restrict__ wot)
{
    __shared__ float t[64][65];
    const int z = blockIdx.z;
    const float* W = (z == 0) ? Wq : (z == 1) ? Wk : (z == 2) ? Wv : Wo;
    __bf16* dst = (z < 3) ? (wqkvt + (size_t)z * D_ * D_) : wot;
    const int k0 = blockIdx.x * 64, n0 = blockIdx.y * 64;
    const int tid = threadIdx.x;
    #pragma unroll
    for (int p = 0; p < 16; ++p) {
        const int idx = p * 256 + tid;
        const int r = idx >> 6, c = idx & 63;
        t[r][c] = W[(size_t)(k0 + r) * D_ + n0 + c];
    }
    __syncthreads();
    #pragma unroll
    for (int p = 0; p < 16; ++p) {
        const int idx = p * 256 + tid;
        const int r = idx >> 6, c = idx & 63;
        dst[(size_t)(n0 + r) * D_ + k0 + c] = (__bf16)t[c][r];
    }
}

// ---------------------------------------------------------------------------
// qkv GEMM v3: true m201-style 8-phase schedule. 256x256 tile, BK=64,
// 8 waves (2Mx4N), double-buffered LDS (128 KB). Each phase: 12 ds_read_b128
// (one C-quadrant) + stage ONE half-tile (2 global_load_lds) -> barrier ->
// setprio(1) 16 MFMA setprio(0) -> barrier. Counted vmcnt(4) only at p3/p7
// (never 0 in steady state). Staging calendar race-screened: each staged
// region's last reader finished >=1 barrier before issue:
//   p0:A(T+1)h1  p1:B(T+1)odd  p2:A(T+2)h0  p3:B(T+2)even [vmcnt4]
//   p4:A(T+2)h1  p5:B(T+2)odd  p6:A(T+3)h0  p7:B(T+3)even [vmcnt4]
// Quadrant q reads A rows half (q>>1) and B col-blocks parity (q&1) only.
// LDS swizzle: chunk c at physical c^(row&7) via pre-swizzled global source.
// ---------------------------------------------------------------------------
__global__ __launch_bounds__(512, 2) void qkv_mfma(
        const __bf16* __restrict__ A, const __bf16* __restrict__ Bt,
        const float* __restrict__ bq, const float* __restrict__ bk,
        const float* __restrict__ bv,
        __bf16* __restrict__ qo, __bf16* __restrict__ ko, __bf16* __restrict__ vo)
{
    __shared__ __align__(16) __bf16 As[2][256 * 64];   // 64 KB
    __shared__ __align__(16) __bf16 Bs[2][256 * 64];   // 64 KB
    const int tid = threadIdx.x;
    const int w = tid >> 6, lane = tid & 63;
    const int l15 = lane & 15, quad = lane >> 4;
    const int wr = w >> 2, wc = w & 3;            // 2x4 wave grid
    const int tm = blockIdx.x * 256;              // M row base
    const int bn = blockIdx.y * 256;              // packed-N row base in Bt

    const __bf16* Ag = A + (size_t)tm * D_;
    const __bf16* Bg = Bt + (size_t)bn * D_;

    f32x4 acc[8][4] = {};

    // stage A half-tile: half 0 = rows {0-63,128-191}, half 1 = {64-127,192-255}
    auto stageAh = [&](int t, int half) {
        const int slot = t & 1;
        const int k0 = t * 64;
        #pragma unroll
        for (int s = 0; s < 2; ++s) {
            const int li = s * 512 + tid;           // 0..1023
            const int rl = li >> 3, cs = li & 7;
            const int r = half * 64 + rl + (rl & 64);
            const int csrc = cs ^ (r & 7);
            async_copy16(Ag + (size_t)r * D_ + k0 + csrc * 8,
                         &As[slot][(r * 8 + cs) * 8]);
        }
    };
    // stage B parity: par 0 = col-blocks {0-31,64-95,128-159,192-223}, par 1 = +32
    auto stageBh = [&](int t, int par) {
        const int slot = t & 1;
        const int k0 = t * 64;
        #pragma unroll
        for (int s = 0; s < 2; ++s) {
            const int li = s * 512 + tid;
            const int cl = li >> 3, cs = li & 7;
            const int col = (cl & 31) + ((cl >> 5) << 6) + par * 32;
            const int csrc = cs ^ (col & 7);
            async_copy16(Bg + (size_t)col * D_ + k0 + csrc * 8,
                         &Bs[slot][(col * 8 + cs) * 8]);
        }
    };

#define QKV_PHASE(Ab, Bb, qq, STAGE_STMT, WAIT_STMT)                          \
    {                                                                         \
        const int ar0 = wr * 128 + ((qq) >> 1) * 64;                          \
        const int bc0 = wc * 64 + ((qq) & 1) * 32;                            \
        bf16x8 af[4][2], bfv[2][2];                                           \
        _Pragma("unroll")                                                     \
        for (int fr = 0; fr < 4; ++fr) {                                      \
            const int row = ar0 + fr * 16 + l15;                              \
            _Pragma("unroll")                                                 \
            for (int ks = 0; ks < 2; ++ks)                                    \
                af[fr][ks] = *reinterpret_cast<const bf16x8*>(                \
                    (Ab) + row * 64 + (((ks * 4 + quad) ^ (row & 7)) * 8));   \
        }                                                                     \
        _Pragma("unroll")                                                     \
        for (int nc = 0; nc < 2; ++nc) {                                      \
            const int col = bc0 + nc * 16 + l15;                              \
            _Pragma("unroll")                                                 \
            for (int ks = 0; ks < 2; ++ks)                                    \
                bfv[nc][ks] = *reinterpret_cast<const bf16x8*>(               \
                    (Bb) + col * 64 + (((ks * 4 + quad) ^ (col & 7)) * 8));   \
        }                                                                     \
        STAGE_STMT;                                                           \
        WAIT_STMT;                                                            \
        asm volatile("s_barrier" ::: "memory");                               \
        __builtin_amdgcn_s_setprio(1);                                        \
        _Pragma("unroll")                                                     \
        for (int fr = 0; fr < 4; ++fr)                                        \
            _Pragma("unroll")                                                 \
            for (int nc = 0; nc < 2; ++nc) {                                  \
                f32x4 c = acc[((qq) >> 1) * 4 + fr][((qq) & 1) * 2 + nc];     \
                c = __builtin_amdgcn_mfma_f32_16x16x32_bf16(af[fr][0], bfv[nc][0], c, 0, 0, 0); \
                c = __builtin_amdgcn_mfma_f32_16x16x32_bf16(af[fr][1], bfv[nc][1], c, 0, 0, 0); \
                acc[((qq) >> 1) * 4 + fr][((qq) & 1) * 2 + nc] = c;           \
            }                                                                 \
        __builtin_amdgcn_s_setprio(0);                                        \
        asm volatile("s_barrier" ::: "memory");                               \
    }

    // prologue: tile 0 fully + tile 1 (A h0, B even) = virtual p6,p7
    stageAh(0, 0); stageAh(0, 1); stageBh(0, 0); stageBh(0, 1);
    stageAh(1, 0); stageBh(1, 0);
    asm volatile("s_waitcnt vmcnt(4)" ::: "memory");   // tile 0 landed
    asm volatile("s_barrier" ::: "memory");

    for (int i = 0; i < 8; ++i) {
        const int T1 = 2 * i + 1;          // odd tile in slot1 this iter
        const bool more = (i < 7);
        const __bf16* A0 = As[0]; const __bf16* B0 = Bs[0];
        const __bf16* A1 = As[1]; const __bf16* B1 = Bs[1];

        // phases 0-3: compute tile 2i (slot0)
        QKV_PHASE(A0, B0, 0, stageAh(T1, 1), ((void)0));
        QKV_PHASE(A0, B0, 1, stageBh(T1, 1), ((void)0));
        QKV_PHASE(A0, B0, 2, if (more) stageAh(T1 + 1, 0), ((void)0));
        QKV_PHASE(A0, B0, 3, if (more) stageBh(T1 + 1, 0),
                  if (more) { asm volatile("s_waitcnt vmcnt(4)" ::: "memory"); }
                  else      { asm volatile("s_waitcnt vmcnt(0)" ::: "memory"); });
        // phases 4-7: compute tile 2i+1 (slot1)
        QKV_PHASE(A1, B1, 0, if (more) stageAh(T1 + 1, 1), ((void)0));
        QKV_PHASE(A1, B1, 1, if (more) stageBh(T1 + 1, 1), ((void)0));
        QKV_PHASE(A1, B1, 2, if (more) stageAh(T1 + 2, 0), ((void)0));
        QKV_PHASE(A1, B1, 3, if (more) stageBh(T1 + 2, 0),
                  if (more) { asm volatile("s_waitcnt vmcnt(4)" ::: "memory"); });
    }
#undef QKV_PHASE

    // ---- epilogue (unchanged from verified v2) ----
    const int z = blockIdx.y >> 2;                 // 0:Q 1:K 2:V
    const float* bias = (z == 0) ? bq : (z == 1) ? bk : bv;
    const int ysec = blockIdx.y & 3;
    const int h = ysec * 4 + wc;                   // head (wave col = one head)
    float bcol[4];
    #pragma unroll
    for (int nc = 0; nc < 4; ++nc) bcol[nc] = bias[h * 64 + nc * 16 + l15];
    const int gr0 = tm + wr * 128;

    if (z < 2) {
        __bf16* dst = (z == 0) ? qo : ko;
        const float sc = (z == 0) ? 0.125f * 1.44269504f : 1.0f;
        #pragma unroll
        for (int mr = 0; mr < 8; ++mr)
            #pragma unroll
            for (int i = 0; i < 4; ++i) {
                const int gr = gr0 + mr * 16 + quad * 4 + i;
                const int b = gr >> 11, tok = gr & (N_ - 1);
                __bf16* row = dst + ((size_t)(b * H_ + h) * N_ + tok) * DH_;
                #pragma unroll
                for (int nc = 0; nc < 4; ++nc)
                    row[nc * 16 + l15] = (__bf16)((acc[mr][nc][i] + bcol[nc]) * sc);
            }
    } else {
        #pragma unroll
        for (int mr = 0; mr < 8; ++mr) {
            const int gr = gr0 + mr * 16 + quad * 4;
            const int b = gr >> 11, tok = gr & (N_ - 1);
            #pragma unroll
            for (int nc = 0; nc < 4; ++nc) {
                const int dh = nc * 16 + l15;
                bf16x4 pv;
                #pragma unroll
                for (int i = 0; i < 4; ++i)
                    pv[i] = (__bf16)(acc[mr][nc][i] + bcol[nc]);
                *reinterpret_cast<bf16x4*>(
                    vo + ((size_t)(b * H_ + h) * DH_ + dh) * N_ + tok) = pv;
            }
        }
    }
}

// ---------------------------------------------------------------------------
// out = ctx(bf16, MxD) @ Wo + bo, fp32 output. (128x128, unchanged)
// ---------------------------------------------------------------------------
__global__ __launch_bounds__(256) void out_mfma(
        const __bf16* __restrict__ A, const __bf16* __restrict__ Bt,
        const float* __restrict__ bias, float* __restrict__ out)
{
    __shared__ __align__(16) __bf16 As[128 * 32];
    __shared__ __align__(16) __bf16 Bs[128 * 32];
    const int tid = threadIdx.x;
    const int w = tid >> 6, lane = tid & 63;
    const int l15 = lane & 15, quad = lane >> 4;
    const int tm = blockIdx.x * 128;
    const int tn = blockIdx.y * 128;

    f32x4 acc[4][4] = {};

    for (int k0 = 0; k0 < D_; k0 += 32) {
        __syncthreads();
        #pragma unroll
        for (int it = 0; it < 2; ++it) {
            const int c = it * 256 + tid;
            const int r = c >> 2, pc = c & 3;
            const int lc = swz(r, pc);
            async_copy16(A + (size_t)(tm + r) * D_ + k0 + lc * 8, As + c * 8);
            async_copy16(Bt + (size_t)(tn + r) * D_ + k0 + lc * 8, Bs + c * 8);
        }
        __syncthreads();

        bf16x8 af[4], bfr[4];
        #pragma unroll
        for (int t = 0; t < 4; ++t) {
            const int row = (w >> 1) * 64 + t * 16 + l15;
            af[t] = *reinterpret_cast<const bf16x8*>(
                As + (row * 4 + swz(row, quad)) * 8);
            const int col = (w & 1) * 64 + t * 16 + l15;
            bfr[t] = *reinterpret_cast<const bf16x8*>(
                Bs + (col * 4 + swz(col, quad)) * 8);
        }
        #pragma unroll
        for (int mt = 0; mt < 4; ++mt)
            #pragma unroll
            for (int nt = 0; nt < 4; ++nt)
                acc[mt][nt] = __builtin_amdgcn_mfma_f32_16x16x32_bf16(
                    af[mt], bfr[nt], acc[mt][nt], 0, 0, 0);
    }

    const int col0 = tn + (w & 1) * 64;
    float bcol[4];
    #pragma unroll
    for (int nt = 0; nt < 4; ++nt) bcol[nt] = bias[col0 + nt * 16 + l15];
    const int gr0 = tm + (w >> 1) * 64;
    #pragma unroll
    for (int mt = 0; mt < 4; ++mt)
        #pragma unroll
        for (int i = 0; i < 4; ++i) {
            const int gr = gr0 + mt * 16 + quad * 4 + i;
            float* row = out + (size_t)gr * D_;
            #pragma unroll
            for (int nt = 0; nt < 4; ++nt)
                row[col0 + nt * 16 + l15] = acc[mt][nt][i] + bcol[nt];
        }
}

// ---------------------------------------------------------------------------
// MFMA flash attention v7 (decorrelated grid + setprio on MFMA clusters).
// ---------------------------------------------------------------------------
__global__ __launch_bounds__(256, 4) void attn(
        const __bf16* __restrict__ Q, const __bf16* __restrict__ K,
        const __bf16* __restrict__ Vt, __bf16* __restrict__ ctx)
{
    const int blk = blockIdx.x;
    const int bh = blk & 63;
    const int qb = ((blk >> 6) + bh) & 15;
    const int tid = threadIdx.x;
    const int w = tid >> 6, lane = tid & 63;
    const int l15 = lane & 15, quad = lane >> 4;
    const int qt0 = qb * 128;

    __shared__ __align__(16) __bf16 Ks[64 * 64];         // [key][d], swizzled
    __shared__ __align__(16) __bf16 Vs[64 * 64];         // [d][key], swizzled
    __shared__ __align__(16) __bf16 Ps[4][2][16 * 72];   // [wave][qc], +8 pad

    bf16x8 bqf[2][2];
    #pragma unroll
    for (int qc = 0; qc < 2; ++qc) {
        const size_t base = ((size_t)bh * N_ + qt0 + w * 32 + qc * 16 + l15) * DH_;
        bqf[qc][0] = *reinterpret_cast<const bf16x8*>(Q + base + quad * 8);
        bqf[qc][1] = *reinterpret_cast<const bf16x8*>(Q + base + 32 + quad * 8);
    }

    f32x4 acc[2][4] = {};
    float l_lane[2] = {0.f, 0.f};

    const __bf16* Kg = K + (size_t)bh * N_ * DH_;
    const __bf16* Vg = Vt + (size_t)bh * DH_ * N_;
    const int nkb = 2 * qb + 2;
    const int sr = lane >> 3;
    const int sc = lane & 7;

    for (int kb = 0; kb < nkb; ++kb) {
        __syncthreads();
        #pragma unroll
        for (int j = 0; j < 2; ++j) {
            const int r = j * 32 + w * 8 + sr;
            const int cl = sc ^ (r & 7);
            async_copy16(Kg + (size_t)(kb * 64 + r) * DH_ + cl * 8,
                         &Ks[(j * 256 + tid) * 8]);
            async_copy16(Vg + (size_t)r * N_ + kb * 64 + cl * 8,
                         &Vs[(j * 256 + tid) * 8]);
        }
        __syncthreads();

        f32x4 st[2][4];
        __builtin_amdgcn_s_setprio(1);
        #pragma unroll
        for (int ct = 0; ct < 4; ++ct) {
            const int row = ct * 16 + l15;
            const bf16x8 ka0 = *reinterpret_cast<const bf16x8*>(
                &Ks[(row * 8 + (quad ^ (row & 7))) * 8]);
            const bf16x8 ka1 = *reinterpret_cast<const bf16x8*>(
                &Ks[(row * 8 + ((quad + 4) ^ (row & 7))) * 8]);
            #pragma unroll
            for (int qc = 0; qc < 2; ++qc) {
                f32x4 t = {};
                t = __builtin_amdgcn_mfma_f32_16x16x32_bf16(ka0, bqf[qc][0], t, 0, 0, 0);
                t = __builtin_amdgcn_mfma_f32_16x16x32_bf16(ka1, bqf[qc][1], t, 0, 0, 0);
                st[qc][ct] = t;
            }
        }
        __builtin_amdgcn_s_setprio(0);
        if (kb >= 2 * qb) {
            #pragma unroll
            for (int qc = 0; qc < 2; ++qc) {
                const int q_glob = qt0 + w * 32 + qc * 16 + l15;
                #pragma unroll
                for (int ct = 0; ct < 4; ++ct)
                    #pragma unroll
                    for (int i = 0; i < 4; ++i) {
                        const int k_glob = kb * 64 + ct * 16 + quad * 4 + i;
                        if (k_glob > q_glob) st[qc][ct][i] = -INFINITY;
                    }
            }
        }

        #pragma unroll
        for (int qc = 0; qc < 2; ++qc) {
            float rs = 0.f;
            #pragma unroll
            for (int ct = 0; ct < 4; ++ct) {
                bf16x4 pk;
                #pragma unroll
                for (int i = 0; i < 4; ++i) {
                    const float p = fast_exp2(st[qc][ct][i]);
                    rs += p;
                    pk[i] = (__bf16)p;
                }
                *reinterpret_cast<bf16x4*>(
                    &Ps[w][qc][l15 * 72 + ct * 16 + quad * 4]) = pk;
            }
            l_lane[qc] += rs;
        }

        bf16x8 pa0[2], pa1[2];
        #pragma unroll
        for (int qc = 0; qc < 2; ++qc) {
            pa0[qc] = *reinterpret_cast<const bf16x8*>(
                &Ps[w][qc][l15 * 72 + quad * 8]);
            pa1[qc] = *reinterpret_cast<const bf16x8*>(
                &Ps[w][qc][l15 * 72 + 32 + quad * 8]);
        }
        __builtin_amdgcn_s_setprio(1);
        #pragma unroll
        for (int ct = 0; ct < 4; ++ct) {
            const int row = ct * 16 + l15;
            const bf16x8 vb0 = *reinterpret_cast<const bf16x8*>(
                &Vs[(row * 8 + (quad ^ (row & 7))) * 8]);
            const bf16x8 vb1 = *reinterpret_cast<const bf16x8*>(
                &Vs[(row * 8 + ((quad + 4) ^ (row & 7))) * 8]);
            #pragma unroll
            for (int qc = 0; qc < 2; ++qc) {
                f32x4 t = acc[qc][ct];
                t = __builtin_amdgcn_mfma_f32_16x16x32_bf16(pa0[qc], vb0, t, 0, 0, 0);
                t = __builtin_amdgcn_mfma_f32_16x16x32_bf16(pa1[qc], vb1, t, 0, 0, 0);
                acc[qc][ct] = t;
            }
        }
        __builtin_amdgcn_s_setprio(0);
    }

    const int b = bh >> 4, h = bh & 15;
    #pragma unroll
    for (int qc = 0; qc < 2; ++qc) {
        float r = l_lane[qc];
        r += __shfl_xor(r, 16);
        r += __shfl_xor(r, 32);
        const float linv = 1.0f / r;
        float lT[4];
        #pragma unroll
        for (int i = 0; i < 4; ++i) lT[i] = __shfl(linv, quad * 4 + i);
        #pragma unroll
        for (int i = 0; i < 4; ++i) {
            const int row = qt0 + w * 32 + qc * 16 + quad * 4 + i;
            __bf16* dst = ctx + ((size_t)b * N_ + row) * D_ + h * DH_;
            #pragma unroll
            for (int ct = 0; ct < 4; ++ct)
                dst[ct * 16 + l15] = (__bf16)(acc[qc][ct][i] * lT[i]);
        }
    }
}

extern "C" void kernel_launch(void* const* d_in, const int* in_sizes, int n_in,
                              void* d_out, int out_size, void* d_ws, size_t ws_size,
                              hipStream_t stream) {
    const float* x  = (const float*)d_in[0];
    const float* Wq = (const float*)d_in[1];
    const float* bq = (const float*)d_in[2];
    const float* Wk = (const float*)d_in[3];
    const float* bk = (const float*)d_in[4];
    const float* Wv = (const float*)d_in[5];
    const float* bv = (const float*)d_in[6];
    const float* Wo = (const float*)d_in[7];
    const float* bo = (const float*)d_in[8];
    float* out = (float*)d_out;

    __bf16* xb    = (__bf16*)d_ws;
    __bf16* wqkvt = xb + (size_t)M_ * D_;
    __bf16* wot   = wqkvt + (size_t)3 * D_ * D_;
    __bf16* q     = wot + (size_t)D_ * D_;
    __bf16* k     = q + (size_t)M_ * D_;
    __bf16* vt    = k + (size_t)M_ * D_;
    __bf16* ctx   = vt + (size_t)M_ * D_;

    cast_x<<<dim3(M_ * D_ / (256 * 8)), 256, 0, stream>>>(x, xb);
    cast_w<<<dim3(16, 16, 4), 256, 0, stream>>>(Wq, Wk, Wv, Wo, wqkvt, wot);
    qkv_mfma<<<dim3(M_ / 256, 3 * D_ / 256), 512, 0, stream>>>(
        xb, wqkvt, bq, bk, bv, q, k, vt);
    attn<<<dim3(1024), 256, 0, stream>>>(q, k, vt, ctx);
    out_mfma<<<dim3(M_ / 128, D_ / 128), 256, 0, stream>>>(ctx, wot, bo, out);
}

// Round 5
// 256.943 us; speedup vs baseline: 1.0405x; 1.0285x over previous
//
#include <hip/hip_runtime.h>
#include <hip/hip_bf16.h>
#include <math.h>

namespace {
constexpr int B_ = 4, N_ = 2048, D_ = 1024, H_ = 16, DH_ = 64;
constexpr int M_ = B_ * N_;   // 8192 rows of x
}

typedef __bf16 bf16x8 __attribute__((ext_vector_type(8)));
typedef __bf16 bf16x4 __attribute__((ext_vector_type(4)));
typedef float  f32x4  __attribute__((ext_vector_type(4)));

__device__ inline void async_copy16(const void* g, void* l) {
    __builtin_amdgcn_global_load_lds(
        (const __attribute__((address_space(1))) unsigned int*)g,
        (__attribute__((address_space(3))) unsigned int*)l, 16, 0, 0);
}

__device__ inline float fast_exp2(float x) {
#if __has_builtin(__builtin_amdgcn_exp2f)
    return __builtin_amdgcn_exp2f(x);
#else
    return exp2f(x);
#endif
}

// XOR swizzle for 128x32 tiles (legacy kernels): 16B chunk column 0..3.
__device__ inline int swz(int row, int c) {
    return c ^ (row & 3) ^ ((row >> 2) & 3);
}

// ---------------------------------------------------------------------------
// cast x (fp32 -> bf16), 8 elements/thread
// ---------------------------------------------------------------------------
__global__ __launch_bounds__(256) void cast_x(
        const float* __restrict__ x, __bf16* __restrict__ xb)
{
    const size_t i = ((size_t)blockIdx.x * 256 + threadIdx.x) * 8;
    const float4 a = *reinterpret_cast<const float4*>(x + i);
    const float4 b = *reinterpret_cast<const float4*>(x + i + 4);
    bf16x8 o;
    o[0] = (__bf16)a.x; o[1] = (__bf16)a.y; o[2] = (__bf16)a.z; o[3] = (__bf16)a.w;
    o[4] = (__bf16)b.x; o[5] = (__bf16)b.y; o[6] = (__bf16)b.z; o[7] = (__bf16)b.w;
    *reinterpret_cast<bf16x8*>(xb + i) = o;
}

// ---------------------------------------------------------------------------
// cast+transpose weights: W[k][n] fp32 -> Wt[n][k] bf16.
// ---------------------------------------------------------------------------
__global__ __launch_bounds__(256) void cast_w(
        const float* __restrict__ Wq, const float* __restrict__ Wk,
        const float* __restrict__ Wv, const float* __restrict__ Wo,
        __bf16* __restrict__ wqkvt, __bf16* __restrict__ wot)
{
    __shared__ float t[64][65];
    const int z = blockIdx.z;
    const float* W = (z == 0) ? Wq : (z == 1) ? Wk : (z == 2) ? Wv : Wo;
    __bf16* dst = (z < 3) ? (wqkvt + (size_t)z * D_ * D_) : wot;
    const int k0 = blockIdx.x * 64, n0 = blockIdx.y * 64;
    const int tid = threadIdx.x;
    #pragma unroll
    for (int p = 0; p < 16; ++p) {
        const int idx = p * 256 + tid;
        const int r = idx >> 6, c = idx & 63;
        t[r][c] = W[(size_t)(k0 + r) * D_ + n0 + c];
    }
    __syncthreads();
    #pragma unroll
    for (int p = 0; p < 16; ++p) {
        const int idx = p * 256 + tid;
        const int r = idx >> 6, c = idx & 63;
        dst[(size_t)(n0 + r) * D_ + k0 + c] = (__bf16)t[c][r];
    }
}

// ---------------------------------------------------------------------------
// qkv GEMM v4: 8-phase schedule with FRAGMENT REUSE (m201 read density).
// 256x256 tile, BK=64, 8 waves (2Mx4N), dbuf LDS 128 KB. Phases are
// (ks-slice x row-half); B-frags read once per ks and REUSED across the two
// half-phases: 24 ds_read_b128 per K-tile (was 48 in v3 -> LDS-BW-bound).
// Per phase: {4 or 8 ds_read_b128} + stage one half-region (2 gload_lds) ->
// barrier -> setprio(1) 16 MFMA setprio(0) -> barrier.
// Staging calendar (iteration i computes tile 2i in p0-3, 2i+1 in p4-7);
// every staged region's last reader finished >=1 barrier before issue:
//   p0: A(2i+1,h1)[s1]  p1: B(2i+1,ev)[s1]  p2: B(2i+1,od)[s1]
//   p3: A(2i+2,h0)[s0: A-h0 readers p0,p2 done]          + vmcnt(2)
//   p4: B(2i+2,ev)[s0 free] p5: B(2i+2,od) p6: A(2i+2,h1)
//   p7: A(2i+3,h0)[s1: A-h0 readers p4,p6 done]          + vmcnt(2)
// vmcnt(2)@p3 -> tile 2i+1 landed before p4; vmcnt(2)@p7 -> tile 2i+2
// landed before next p0. Never vmcnt(0) except tail. LDS chunk swizzle
// c^(row&7) via pre-swizzled global source (linear gload_lds dest).
// ---------------------------------------------------------------------------
__global__ __launch_bounds__(512, 2) void qkv_mfma(
        const __bf16* __restrict__ A, const __bf16* __restrict__ Bt,
        const float* __restrict__ bq, const float* __restrict__ bk,
        const float* __restrict__ bv,
        __bf16* __restrict__ qo, __bf16* __restrict__ ko, __bf16* __restrict__ vo)
{
    __shared__ __align__(16) __bf16 As[2][256 * 64];   // 64 KB
    __shared__ __align__(16) __bf16 Bs[2][256 * 64];   // 64 KB
    const int tid = threadIdx.x;
    const int w = tid >> 6, lane = tid & 63;
    const int l15 = lane & 15, quad = lane >> 4;
    const int wr = w >> 2, wc = w & 3;            // 2x4 wave grid
    const int tm = blockIdx.x * 256;              // M row base
    const int bn = blockIdx.y * 256;              // packed-N row base in Bt

    const __bf16* Ag = A + (size_t)tm * D_;
    const __bf16* Bg = Bt + (size_t)bn * D_;

    f32x4 acc[8][4] = {};

    // stage A half-tile: half 0 = rows {0-63,128-191}, half 1 = {64-127,192-255}
    auto stageAh = [&](int t, int half) {
        const int slot = t & 1;
        const int k0 = t * 64;
        #pragma unroll
        for (int s = 0; s < 2; ++s) {
            const int li = s * 512 + tid;           // 0..1023
            const int rl = li >> 3, cs = li & 7;
            const int r = half * 64 + rl + (rl & 64);
            const int csrc = cs ^ (r & 7);
            async_copy16(Ag + (size_t)r * D_ + k0 + csrc * 8,
                         &As[slot][(r * 8 + cs) * 8]);
        }
    };
    // stage B parity: par 0 = col-blocks {0-31,64-95,128-159,192-223}, par 1 = +32
    auto stageBh = [&](int t, int par) {
        const int slot = t & 1;
        const int k0 = t * 64;
        #pragma unroll
        for (int s = 0; s < 2; ++s) {
            const int li = s * 512 + tid;
            const int cl = li >> 3, cs = li & 7;
            const int col = (cl & 31) + ((cl >> 5) << 6) + par * 32;
            const int csrc = cs ^ (col & 7);
            async_copy16(Bg + (size_t)col * D_ + k0 + csrc * 8,
                         &Bs[slot][(col * 8 + cs) * 8]);
        }
    };

#define QKV_PHASE(Ab, Bb, KS, HALF, READB, STAGE_STMT, WAIT_STMT)             \
    {                                                                         \
        const int ar0 = wr * 128 + (HALF) * 64;                               \
        bf16x8 af[4];                                                         \
        _Pragma("unroll")                                                     \
        for (int fr = 0; fr < 4; ++fr) {                                      \
            const int row = ar0 + fr * 16 + l15;                              \
            af[fr] = *reinterpret_cast<const bf16x8*>(                        \
                (Ab) + row * 64 + ((((KS) * 4 + quad) ^ (row & 7)) * 8));     \
        }                                                                     \
        if (READB) {                                                          \
            _Pragma("unroll")                                                 \
            for (int nc = 0; nc < 4; ++nc) {                                  \
                const int col = wc * 64 + nc * 16 + l15;                      \
                bfv[nc] = *reinterpret_cast<const bf16x8*>(                   \
                    (Bb) + col * 64 + ((((KS) * 4 + quad) ^ (col & 7)) * 8)); \
            }                                                                 \
        }                                                                     \
        STAGE_STMT;                                                           \
        WAIT_STMT;                                                            \
        asm volatile("s_barrier" ::: "memory");                               \
        __builtin_amdgcn_s_setprio(1);                                        \
        _Pragma("unroll")                                                     \
        for (int fr = 0; fr < 4; ++fr)                                        \
            _Pragma("unroll")                                                 \
            for (int nc = 0; nc < 4; ++nc)                                    \
                acc[(HALF) * 4 + fr][nc] =                                    \
                    __builtin_amdgcn_mfma_f32_16x16x32_bf16(                  \
                        af[fr], bfv[nc], acc[(HALF) * 4 + fr][nc], 0, 0, 0);  \
        __builtin_amdgcn_s_setprio(0);                                        \
        asm volatile("s_barrier" ::: "memory");                               \
    }

    // prologue: tile 0 fully + tile 1 A-h0 (plays the role of p7(i-1))
    stageAh(0, 0); stageAh(0, 1); stageBh(0, 0); stageBh(0, 1);
    stageAh(1, 0);
    asm volatile("s_waitcnt vmcnt(2)" ::: "memory");   // tile 0 landed
    asm volatile("s_barrier" ::: "memory");
    __builtin_amdgcn_sched_barrier(0);

    for (int i = 0; i < 8; ++i) {
        const bool more = (i < 7);
        const __bf16* A0 = As[0]; const __bf16* B0 = Bs[0];
        const __bf16* A1 = As[1]; const __bf16* B1 = Bs[1];
        bf16x8 bfv[4];
        // phases 0-3: compute tile 2i (slot0); ks-major, B reused per ks
        QKV_PHASE(A0, B0, 0, 0, true,  stageAh(2 * i + 1, 1), ((void)0));
        QKV_PHASE(A0, B0, 0, 1, false, stageBh(2 * i + 1, 0), ((void)0));
        QKV_PHASE(A0, B0, 1, 0, true,  stageBh(2 * i + 1, 1), ((void)0));
        QKV_PHASE(A0, B0, 1, 1, false, if (more) stageAh(2 * i + 2, 0),
                  if (more) { asm volatile("s_waitcnt vmcnt(2)" ::: "memory"); }
                  else      { asm volatile("s_waitcnt vmcnt(0)" ::: "memory"); });
        // phases 4-7: compute tile 2i+1 (slot1)
        QKV_PHASE(A1, B1, 0, 0, true,  if (more) stageBh(2 * i + 2, 0), ((void)0));
        QKV_PHASE(A1, B1, 0, 1, false, if (more) stageBh(2 * i + 2, 1), ((void)0));
        QKV_PHASE(A1, B1, 1, 0, true,  if (more) stageAh(2 * i + 2, 1), ((void)0));
        QKV_PHASE(A1, B1, 1, 1, false, if (more) stageAh(2 * i + 3, 0),
                  if (more) { asm volatile("s_waitcnt vmcnt(2)" ::: "memory"); });
    }
#undef QKV_PHASE

    // ---- epilogue (unchanged, verified) ----
    const int z = blockIdx.y >> 2;                 // 0:Q 1:K 2:V
    const float* bias = (z == 0) ? bq : (z == 1) ? bk : bv;
    const int ysec = blockIdx.y & 3;
    const int h = ysec * 4 + wc;                   // head (wave col = one head)
    float bcol[4];
    #pragma unroll
    for (int nc = 0; nc < 4; ++nc) bcol[nc] = bias[h * 64 + nc * 16 + l15];
    const int gr0 = tm + wr * 128;

    if (z < 2) {
        __bf16* dst = (z == 0) ? qo : ko;
        const float sc = (z == 0) ? 0.125f * 1.44269504f : 1.0f;
        #pragma unroll
        for (int mr = 0; mr < 8; ++mr)
            #pragma unroll
            for (int i = 0; i < 4; ++i) {
                const int gr = gr0 + mr * 16 + quad * 4 + i;
                const int b = gr >> 11, tok = gr & (N_ - 1);
                __bf16* row = dst + ((size_t)(b * H_ + h) * N_ + tok) * DH_;
                #pragma unroll
                for (int nc = 0; nc < 4; ++nc)
                    row[nc * 16 + l15] = (__bf16)((acc[mr][nc][i] + bcol[nc]) * sc);
            }
    } else {
        #pragma unroll
        for (int mr = 0; mr < 8; ++mr) {
            const int gr = gr0 + mr * 16 + quad * 4;
            const int b = gr >> 11, tok = gr & (N_ - 1);
            #pragma unroll
            for (int nc = 0; nc < 4; ++nc) {
                const int dh = nc * 16 + l15;
                bf16x4 pv;
                #pragma unroll
                for (int i = 0; i < 4; ++i)
                    pv[i] = (__bf16)(acc[mr][nc][i] + bcol[nc]);
                *reinterpret_cast<bf16x4*>(
                    vo + ((size_t)(b * H_ + h) * DH_ + dh) * N_ + tok) = pv;
            }
        }
    }
}

// ---------------------------------------------------------------------------
// out = ctx(bf16, MxD) @ Wo + bo, fp32 output. (128x128, unchanged)
// ---------------------------------------------------------------------------
__global__ __launch_bounds__(256) void out_mfma(
        const __bf16* __restrict__ A, const __bf16* __restrict__ Bt,
        const float* __restrict__ bias, float* __restrict__ out)
{
    __shared__ __align__(16) __bf16 As[128 * 32];
    __shared__ __align__(16) __bf16 Bs[128 * 32];
    const int tid = threadIdx.x;
    const int w = tid >> 6, lane = tid & 63;
    const int l15 = lane & 15, quad = lane >> 4;
    const int tm = blockIdx.x * 128;
    const int tn = blockIdx.y * 128;

    f32x4 acc[4][4] = {};

    for (int k0 = 0; k0 < D_; k0 += 32) {
        __syncthreads();
        #pragma unroll
        for (int it = 0; it < 2; ++it) {
            const int c = it * 256 + tid;
            const int r = c >> 2, pc = c & 3;
            const int lc = swz(r, pc);
            async_copy16(A + (size_t)(tm + r) * D_ + k0 + lc * 8, As + c * 8);
            async_copy16(Bt + (size_t)(tn + r) * D_ + k0 + lc * 8, Bs + c * 8);
        }
        __syncthreads();

        bf16x8 af[4], bfr[4];
        #pragma unroll
        for (int t = 0; t < 4; ++t) {
            const int row = (w >> 1) * 64 + t * 16 + l15;
            af[t] = *reinterpret_cast<const bf16x8*>(
                As + (row * 4 + swz(row, quad)) * 8);
            const int col = (w & 1) * 64 + t * 16 + l15;
            bfr[t] = *reinterpret_cast<const bf16x8*>(
                Bs + (col * 4 + swz(col, quad)) * 8);
        }
        #pragma unroll
        for (int mt = 0; mt < 4; ++mt)
            #pragma unroll
            for (int nt = 0; nt < 4; ++nt)
                acc[mt][nt] = __builtin_amdgcn_mfma_f32_16x16x32_bf16(
                    af[mt], bfr[nt], acc[mt][nt], 0, 0, 0);
    }

    const int col0 = tn + (w & 1) * 64;
    float bcol[4];
    #pragma unroll
    for (int nt = 0; nt < 4; ++nt) bcol[nt] = bias[col0 + nt * 16 + l15];
    const int gr0 = tm + (w >> 1) * 64;
    #pragma unroll
    for (int mt = 0; mt < 4; ++mt)
        #pragma unroll
        for (int i = 0; i < 4; ++i) {
            const int gr = gr0 + mt * 16 + quad * 4 + i;
            float* row = out + (size_t)gr * D_;
            #pragma unroll
            for (int nt = 0; nt < 4; ++nt)
                row[col0 + nt * 16 + l15] = acc[mt][nt][i] + bcol[nt];
        }
}

// ---------------------------------------------------------------------------
// MFMA flash attention v7 (decorrelated grid + setprio on MFMA clusters).
// ---------------------------------------------------------------------------
__global__ __launch_bounds__(256, 4) void attn(
        const __bf16* __restrict__ Q, const __bf16* __restrict__ K,
        const __bf16* __restrict__ Vt, __bf16* __restrict__ ctx)
{
    const int blk = blockIdx.x;
    const int bh = blk & 63;
    const int qb = ((blk >> 6) + bh) & 15;
    const int tid = threadIdx.x;
    const int w = tid >> 6, lane = tid & 63;
    const int l15 = lane & 15, quad = lane >> 4;
    const int qt0 = qb * 128;

    __shared__ __align__(16) __bf16 Ks[64 * 64];         // [key][d], swizzled
    __shared__ __align__(16) __bf16 Vs[64 * 64];         // [d][key], swizzled
    __shared__ __align__(16) __bf16 Ps[4][2][16 * 72];   // [wave][qc], +8 pad

    bf16x8 bqf[2][2];
    #pragma unroll
    for (int qc = 0; qc < 2; ++qc) {
        const size_t base = ((size_t)bh * N_ + qt0 + w * 32 + qc * 16 + l15) * DH_;
        bqf[qc][0] = *reinterpret_cast<const bf16x8*>(Q + base + quad * 8);
        bqf[qc][1] = *reinterpret_cast<const bf16x8*>(Q + base + 32 + quad * 8);
    }

    f32x4 acc[2][4] = {};
    float l_lane[2] = {0.f, 0.f};

    const __bf16* Kg = K + (size_t)bh * N_ * DH_;
    const __bf16* Vg = Vt + (size_t)bh * DH_ * N_;
    const int nkb = 2 * qb + 2;
    const int sr = lane >> 3;
    const int sc = lane & 7;

    for (int kb = 0; kb < nkb; ++kb) {
        __syncthreads();
        #pragma unroll
        for (int j = 0; j < 2; ++j) {
            const int r = j * 32 + w * 8 + sr;
            const int cl = sc ^ (r & 7);
            async_copy16(Kg + (size_t)(kb * 64 + r) * DH_ + cl * 8,
                         &Ks[(j * 256 + tid) * 8]);
            async_copy16(Vg + (size_t)r * N_ + kb * 64 + cl * 8,
                         &Vs[(j * 256 + tid) * 8]);
        }
        __syncthreads();

        f32x4 st[2][4];
        __builtin_amdgcn_s_setprio(1);
        #pragma unroll
        for (int ct = 0; ct < 4; ++ct) {
            const int row = ct * 16 + l15;
            const bf16x8 ka0 = *reinterpret_cast<const bf16x8*>(
                &Ks[(row * 8 + (quad ^ (row & 7))) * 8]);
            const bf16x8 ka1 = *reinterpret_cast<const bf16x8*>(
                &Ks[(row * 8 + ((quad + 4) ^ (row & 7))) * 8]);
            #pragma unroll
            for (int qc = 0; qc < 2; ++qc) {
                f32x4 t = {};
                t = __builtin_amdgcn_mfma_f32_16x16x32_bf16(ka0, bqf[qc][0], t, 0, 0, 0);
                t = __builtin_amdgcn_mfma_f32_16x16x32_bf16(ka1, bqf[qc][1], t, 0, 0, 0);
                st[qc][ct] = t;
            }
        }
        __builtin_amdgcn_s_setprio(0);
        if (kb >= 2 * qb) {
            #pragma unroll
            for (int qc = 0; qc < 2; ++qc) {
                const int q_glob = qt0 + w * 32 + qc * 16 + l15;
                #pragma unroll
                for (int ct = 0; ct < 4; ++ct)
                    #pragma unroll
                    for (int i = 0; i < 4; ++i) {
                        const int k_glob = kb * 64 + ct * 16 + quad * 4 + i;
                        if (k_glob > q_glob) st[qc][ct][i] = -INFINITY;
                    }
            }
        }

        #pragma unroll
        for (int qc = 0; qc < 2; ++qc) {
            float rs = 0.f;
            #pragma unroll
            for (int ct = 0; ct < 4; ++ct) {
                bf16x4 pk;
                #pragma unroll
                for (int i = 0; i < 4; ++i) {
                    const float p = fast_exp2(st[qc][ct][i]);
                    rs += p;
                    pk[i] = (__bf16)p;
                }
                *reinterpret_cast<bf16x4*>(
                    &Ps[w][qc][l15 * 72 + ct * 16 + quad * 4]) = pk;
            }
            l_lane[qc] += rs;
        }

        bf16x8 pa0[2], pa1[2];
        #pragma unroll
        for (int qc = 0; qc < 2; ++qc) {
            pa0[qc] = *reinterpret_cast<const bf16x8*>(
                &Ps[w][qc][l15 * 72 + quad * 8]);
            pa1[qc] = *reinterpret_cast<const bf16x8*>(
                &Ps[w][qc][l15 * 72 + 32 + quad * 8]);
        }
        __builtin_amdgcn_s_setprio(1);
        #pragma unroll
        for (int ct = 0; ct < 4; ++ct) {
            const int row = ct * 16 + l15;
            const bf16x8 vb0 = *reinterpret_cast<const bf16x8*>(
                &Vs[(row * 8 + (quad ^ (row & 7))) * 8]);
            const bf16x8 vb1 = *reinterpret_cast<const bf16x8*>(
                &Vs[(row * 8 + ((quad + 4) ^ (row & 7))) * 8]);
            #pragma unroll
            for (int qc = 0; qc < 2; ++qc) {
                f32x4 t = acc[qc][ct];
                t = __builtin_amdgcn_mfma_f32_16x16x32_bf16(pa0[qc], vb0, t, 0, 0, 0);
                t = __builtin_amdgcn_mfma_f32_16x16x32_bf16(pa1[qc], vb1, t, 0, 0, 0);
                acc[qc][ct] = t;
            }
        }
        __builtin_amdgcn_s_setprio(0);
    }

    const int b = bh >> 4, h = bh & 15;
    #pragma unroll
    for (int qc = 0; qc < 2; ++qc) {
        float r = l_lane[qc];
        r += __shfl_xor(r, 16);
        r += __shfl_xor(r, 32);
        const float linv = 1.0f / r;
        float lT[4];
        #pragma unroll
        for (int i = 0; i < 4; ++i) lT[i] = __shfl(linv, quad * 4 + i);
        #pragma unroll
        for (int i = 0; i < 4; ++i) {
            const int row = qt0 + w * 32 + qc * 16 + quad * 4 + i;
            __bf16* dst = ctx + ((size_t)b * N_ + row) * D_ + h * DH_;
            #pragma unroll
            for (int ct = 0; ct < 4; ++ct)
                dst[ct * 16 + l15] = (__bf16)(acc[qc][ct][i] * lT[i]);
        }
    }
}

extern "C" void kernel_launch(void* const* d_in, const int* in_sizes, int n_in,
                              void* d_out, int out_size, void* d_ws, size_t ws_size,
                              hipStream_t stream) {
    const float* x  = (const float*)d_in[0];
    const float* Wq = (const float*)d_in[1];
    const float* bq = (const float*)d_in[2];
    const float* Wk = (const float*)d_in[3];
    const float* bk = (const float*)d_in[4];
    const float* Wv = (const float*)d_in[5];
    const float* bv = (const float*)d_in[6];
    const float* Wo = (const float*)d_in[7];
    const float* bo = (const float*)d_in[8];
    float* out = (float*)d_out;

    __bf16* xb    = (__bf16*)d_ws;
    __bf16* wqkvt = xb + (size_t)M_ * D_;
    __bf16* wot   = wqkvt + (size_t)3 * D_ * D_;
    __bf16* q     = wot + (size_t)D_ * D_;
    __bf16* k     = q + (size_t)M_ * D_;
    __bf16* vt    = k + (size_t)M_ * D_;
    __bf16* ctx   = vt + (size_t)M_ * D_;

    cast_x<<<dim3(M_ * D_ / (256 * 8)), 256, 0, stream>>>(x, xb);
    cast_w<<<dim3(16, 16, 4), 256, 0, stream>>>(Wq, Wk, Wv, Wo, wqkvt, wot);
    qkv_mfma<<<dim3(M_ / 256, 3 * D_ / 256), 512, 0, stream>>>(
        xb, wqkvt, bq, bk, bv, q, k, vt);
    attn<<<dim3(1024), 256, 0, stream>>>(q, k, vt, ctx);
    out_mfma<<<dim3(M_ / 128, D_ / 128), 256, 0, stream>>>(ctx, wot, bo, out);
}